// Round 12
// baseline (107.053 us; speedup 1.0000x reference)
//
#include <hip/hip_runtime.h>
#include <cstdint>

constexpr int B  = 4;
constexpr int C  = 128;
constexpr int CM = 32;        // mid channels
constexpr int H  = 160;
constexpr int W  = 160;
constexpr int HW = H * W;     // 25600
constexpr int HP = H + 1;     // 161
constexpr int WP = W + 1;     // 161
constexpr int PLANE = HP * WP; // 25921
constexpr int TY = 16;         // rows per box tile
constexpr int NTILE = H / TY;  // 10
constexpr int PB  = 64;        // positions per conv block
constexpr int K1B = B * HW / PB; // 1600 conv blocks
constexpr int NB2 = B * NTILE; // 40 partials per out-channel
constexpr int QR = 40;         // rows per scan quarter

// ---------------- K0: transpose w1 [CM][C] -> wTg [C][CM] (16 KB, once) ----------------
__global__ __launch_bounds__(256) void k_transpose_w(
    const float* __restrict__ w1, float* __restrict__ wTg)
{
    int t = blockIdx.x * 256 + threadIdx.x;    // 4096 elements
    if (t < C * CM) {
        int o = t / C, c = t % C;
        wTg[c * CM + o] = w1[t];
    }
}

// ------- K1: 1x1 conv, split-C: wave q owns c in [32q,32q+32), 64 pos/block -------
__global__ __launch_bounds__(256) void k_conv(
    const float* __restrict__ x, const float* __restrict__ wTg,
    float* __restrict__ h, float* __restrict__ part1)
{
    __shared__ float part[4 * CM * PB];   // 32 KB: [q][o][lane]
    int tid = threadIdx.x;
    int wave = tid >> 6, lane = tid & 63;
    int bid = blockIdx.x;                 // 1600 blocks; 400 per batch image
    int b = bid / 400;
    int p0 = (bid % 400) * PB;

    int wq = __builtin_amdgcn_readfirstlane(wave);   // uniform wave id -> SGPR
    const float* xb = x + (size_t)b * C * HW + (size_t)(wq * 32) * HW + p0 + lane;
    const float* wrow = wTg + (size_t)(wq * 32) * CM;  // uniform base -> s_loads

    float acc[CM];
    #pragma unroll
    for (int o = 0; o < CM; ++o) acc[o] = 0.f;

    #pragma unroll 4
    for (int i = 0; i < 32; ++i) {
        float xv = xb[(size_t)i * HW];               // coalesced 256B vector load
        const float* wr = wrow + i * CM;             // uniform -> scalar loads
        #pragma unroll
        for (int o = 0; o < CM; ++o)
            acc[o] = fmaf(wr[o], xv, acc[o]);        // SGPR-operand FMA
    }

    float* pq = &part[wave * CM * PB];
    #pragma unroll
    for (int o = 0; o < CM; ++o) pq[o * PB + lane] = acc[o];
    __syncthreads();

    // final: thread t owns 8 consecutive finals (one o, lanes l0..l0+7)
    int o  = tid >> 3;                 // 0..31
    int l0 = (tid & 7) * 8;
    const float* pp = &part[o * PB + l0];
    float4 f0 = *reinterpret_cast<const float4*>(pp);
    float4 f1 = *reinterpret_cast<const float4*>(pp + 4);
    #pragma unroll
    for (int q = 1; q < 4; ++q) {
        const float4 a0 = *reinterpret_cast<const float4*>(pp + q * CM * PB);
        const float4 a1 = *reinterpret_cast<const float4*>(pp + q * CM * PB + 4);
        f0.x += a0.x; f0.y += a0.y; f0.z += a0.z; f0.w += a0.w;
        f1.x += a1.x; f1.y += a1.y; f1.z += a1.z; f1.w += a1.w;
    }

    float* hb = h + ((size_t)(b * CM + o)) * HW + p0 + l0;
    *reinterpret_cast<float4*>(hb)     = f0;
    *reinterpret_cast<float4*>(hb + 4) = f1;

    float s  = f0.x + f0.y + f0.z + f0.w + f1.x + f1.y + f1.z + f1.w;
    float s2 = f0.x * f0.x + f0.y * f0.y + f0.z * f0.z + f0.w * f0.w
             + f1.x * f1.x + f1.y * f1.y + f1.z * f1.z + f1.w * f1.w;
    #pragma unroll
    for (int off = 4; off > 0; off >>= 1) {
        s  += __shfl_down(s,  off, 8);
        s2 += __shfl_down(s2, off, 8);
    }
    if ((tid & 7) == 0) {
        part1[(size_t)o * K1B + bid]        = s;   // row o      : sums
        part1[(size_t)(o + CM) * K1B + bid] = s2;  // row CM + o : sumsq
    }
}

// ---------------- R1: parallel row-sums (64 blocks, coalesced) ----------------
__global__ __launch_bounds__(256) void k_rowsum1(
    const float* __restrict__ part1, double* __restrict__ rowsum1)
{
    __shared__ double red[256];
    int tid = threadIdx.x;
    int r = blockIdx.x;                      // 0..63
    const float* row = part1 + (size_t)r * K1B;
    double a = 0.0;
    for (int i = tid; i < K1B; i += 256) a += (double)row[i];
    red[tid] = a;
    __syncthreads();
    #pragma unroll
    for (int s = 128; s > 0; s >>= 1) {
        if (tid < s) red[tid] += red[tid + s];
        __syncthreads();
    }
    if (tid == 0) rowsum1[r] = red[0];
}

// ------- K2: BN1 (from rowsum1) + ReLU + row scan + LOCAL col scan per (plane, quarter) -------
__global__ __launch_bounds__(256) void k_scan_part(
    const float* __restrict__ h, const double* __restrict__ rowsum1,
    const float* __restrict__ g1, const float* __restrict__ b1,
    float* __restrict__ II, float* __restrict__ qlast)
{
    __shared__ float buf[QR * W];   // 40 row-scanned rows, 25600 B
    int tid = threadIdx.x;
    int wave = tid >> 6, lane = tid & 63;
    int blk = blockIdx.x;           // plane*4 + q
    int plane = blk >> 2, q = blk & 3;
    int cm = plane & (CM - 1);

    double n = (double)(B * HW);
    double mean = rowsum1[cm] / n;
    double var  = rowsum1[CM + cm] / n - mean * mean;
    float inv   = (float)(1.0 / sqrt(var + 1e-5));
    float scale = g1[cm] * inv;
    float shift = b1[cm] - (float)mean * scale;

    const float* hp = h + (size_t)plane * HW + (size_t)q * QR * W;
    float* IIp = II + (size_t)plane * PLANE;

    if (q == 0) {
        for (int e = tid; e < WP; e += 256) IIp[e] = 0.f;
    }

    for (int y = wave; y < QR; y += 4) {
        const float* hr = hp + (size_t)y * W;
        float carry = 0.f;
        #pragma unroll
        for (int x0 = 0; x0 < W; x0 += 64) {
            int xx = x0 + lane;
            float v = (xx < W) ? fmaxf(fmaf(scale, hr[xx], shift), 0.f) : 0.f;
            #pragma unroll
            for (int off = 1; off < 64; off <<= 1) {
                float t = __shfl_up(v, off);
                if (lane >= off) v += t;
            }
            v += carry;
            if (xx < W) buf[y * W + xx] = v;
            carry = __shfl(v, 63);
        }
    }
    __syncthreads();

    float* op = IIp + (size_t)(q * QR + 1) * WP;
    float* ql = qlast + ((size_t)plane * 3 + q) * WP;
    if (tid <= W) {
        float run = 0.f;
        #pragma unroll 4
        for (int r = 0; r < QR; ++r) {
            float v = 0.f;
            if (tid > 0) { run += buf[r * W + (tid - 1)]; v = run; }
            op[(size_t)r * WP + tid] = v;
            if (r == QR - 1 && q < 3) ql[tid] = v;
        }
    }
}

// ---------------- box tile machinery ----------------
struct BoxSmem {
    float D[TY][WP];      // row-interp difference rows (true II values)
    float coff[4][WP];    // cumulative cross-quarter offsets per column
    int   ru0[2][TY];     // [0]=lo, [1]=hi row coords
    int   ru1[2][TY];
    float rua[2][TY];
    int   rq0[2][TY];     // quarter index of ru0 / ru1
    int   rq1[2][TY];
};

__device__ inline int qidx(int row) { return row == 0 ? 0 : (row - 1) / QR; }

__device__ inline void fill_D(BoxSmem& sm, const float* __restrict__ II,
    const float* __restrict__ qlast,
    int tile, int k, int b,
    const float* __restrict__ xmin, const float* __restrict__ xmax)
{
    int tid = threadIdx.x;
    int plane = b * CM + (k >> 2);
    if (tid < 2 * TY) {
        int side = tid / TY, ty = tid % TY;
        float off = side ? (xmax[k] + 1.f) : xmin[k];
        float u = fminf(fmaxf((float)(tile * TY + ty) + off, 0.f), 160.f);
        float uf = floorf(u);
        int i0 = (int)uf;
        int i1 = min(i0 + 1, 160);
        sm.ru0[side][ty] = i0;
        sm.ru1[side][ty] = i1;
        sm.rua[side][ty] = u - uf;
        sm.rq0[side][ty] = qidx(i0);
        sm.rq1[side][ty] = qidx(i1);
    }
    {
        const float* qb = qlast + (size_t)plane * 3 * WP;
        for (int v = tid; v < WP; v += 256) {
            float l0 = qb[v], l1 = qb[WP + v], l2 = qb[2 * WP + v];
            sm.coff[0][v] = 0.f;
            sm.coff[1][v] = l0;
            sm.coff[2][v] = l0 + l1;
            sm.coff[3][v] = l0 + l1 + l2;
        }
    }
    __syncthreads();

    const float* P = II + (size_t)plane * PLANE;
    int ty = tid / WP, v = tid % WP;
    for (int e = tid; e < TY * WP; e += 256) {
        float al = sm.rua[0][ty], ah = sm.rua[1][ty];
        float lo = (P[(size_t)sm.ru0[0][ty] * WP + v] + sm.coff[sm.rq0[0][ty]][v]) * (1.f - al)
                 + (P[(size_t)sm.ru1[0][ty] * WP + v] + sm.coff[sm.rq1[0][ty]][v]) * al;
        float hi = (P[(size_t)sm.ru0[1][ty] * WP + v] + sm.coff[sm.rq0[1][ty]][v]) * (1.f - ah)
                 + (P[(size_t)sm.ru1[1][ty] * WP + v] + sm.coff[sm.rq1[1][ty]][v]) * ah;
        sm.D[ty][v] = hi - lo;
        ty += 1; v += 95;
        if (v >= WP) { v -= WP; ty += 1; }
    }
    __syncthreads();
}

// per-column hoisted coords
struct ColW { int l0, l1, h0, h1; float la, ha; };

__device__ inline ColW mk_colw(int xx, float ylo, float yhi)
{
    ColW c;
    float v = fminf(fmaxf((float)xx + ylo, 0.f), 160.f);
    float vf = floorf(v);
    c.l0 = (int)vf; c.la = v - vf; c.l1 = min(c.l0 + 1, 160);
    v = fminf(fmaxf((float)xx + yhi, 0.f), 160.f);
    vf = floorf(v);
    c.h0 = (int)vf; c.ha = v - vf; c.h1 = min(c.h0 + 1, 160);
    return c;
}

__device__ inline float eval_col(const BoxSmem& sm, int ty, const ColW& c)
{
    const float* Dr = sm.D[ty];
    return (Dr[c.h0] * (1.f - c.ha) + Dr[c.h1] * c.ha)
         - (Dr[c.l0] * (1.f - c.la) + Dr[c.l1] * c.la);
}

// ---------------- K4: box conv -> BN2 partial stats ----------------
// eval split: t<160 own col t, rows 0..9 (hoisted ColW); t>=160 cover rows 10..15
__global__ __launch_bounds__(256) void k_box_part(
    const float* __restrict__ II, const float* __restrict__ qlast,
    const float* __restrict__ xmin, const float* __restrict__ xmax,
    const float* __restrict__ ymin, const float* __restrict__ ymax,
    float* __restrict__ part2)
{
    __shared__ BoxSmem sm;
    __shared__ float red[4][2];
    int tile = blockIdx.x, k = blockIdx.y, b = blockIdx.z;
    float ylo = ymin[k], yhi = ymax[k] + 1.f;     // hoisted scalar loads
    fill_D(sm, II, qlast, tile, k, b, xmin, xmax);

    int tid = threadIdx.x;
    float s = 0.f, s2 = 0.f;
    if (tid < W) {
        ColW c = mk_colw(tid, ylo, yhi);
        #pragma unroll
        for (int ty = 0; ty < 10; ++ty) {
            float v = eval_col(sm, ty, c);
            s  += v;
            s2 += v * v;
        }
    } else {
        int t0 = tid - W;                          // 0..95
        #pragma unroll
        for (int j = 0; j < 10; ++j) {
            int e = t0 + 96 * j;                   // 0..959
            int row = 10 + e / 160;
            int col = e - (e / 160) * 160;
            ColW c = mk_colw(col, ylo, yhi);
            float v = eval_col(sm, row, c);
            s  += v;
            s2 += v * v;
        }
    }
    #pragma unroll
    for (int off = 32; off > 0; off >>= 1) {
        s  += __shfl_down(s,  off);
        s2 += __shfl_down(s2, off);
    }
    int wave = tid >> 6, lane = tid & 63;
    if (lane == 0) { red[wave][0] = s; red[wave][1] = s2; }
    __syncthreads();
    if (tid == 0) {
        int idx = b * NTILE + tile;     // 0..39
        part2[(size_t)k * NB2 + idx]       = red[0][0] + red[1][0] + red[2][0] + red[3][0];
        part2[(size_t)(C + k) * NB2 + idx] = red[0][1] + red[1][1] + red[2][1] + red[3][1];
    }
}

// ---------------- R2: deterministic reduction -> BN2 scale/shift ----------------
__global__ __launch_bounds__(256) void k_reduce2(
    const float* __restrict__ part2, const float* __restrict__ g2,
    const float* __restrict__ b2, float* __restrict__ sc2)
{
    __shared__ double dsum[2 * C];
    int t = threadIdx.x;                 // 256 rows, one per thread
    const float4* rp = reinterpret_cast<const float4*>(part2 + (size_t)t * NB2);
    double acc = 0.0;
    #pragma unroll
    for (int i = 0; i < NB2 / 4; ++i) {
        float4 v = rp[i];
        acc += (double)v.x + (double)v.y + (double)v.z + (double)v.w;
    }
    dsum[t] = acc;
    __syncthreads();
    if (t < C) {
        double n = (double)(B * HW);
        double mean = dsum[t] / n;
        double var  = dsum[C + t] / n - mean * mean;
        float inv   = (float)(1.0 / sqrt(var + 1e-5));
        float scale = g2[t] * inv;
        sc2[t]     = scale;
        sc2[C + t] = b2[t] - (float)mean * scale;
    }
}

// ---------------- K5: box conv again, BN2, relu(x + h) ----------------
__global__ __launch_bounds__(256) void k_box_final(
    const float* __restrict__ II, const float* __restrict__ qlast,
    const float* __restrict__ x,
    const float* __restrict__ xmin, const float* __restrict__ xmax,
    const float* __restrict__ ymin, const float* __restrict__ ymax,
    const float* __restrict__ sc2, float* __restrict__ out)
{
    __shared__ BoxSmem sm;
    int tile = blockIdx.x, k = blockIdx.y, b = blockIdx.z;
    float ylo = ymin[k], yhi = ymax[k] + 1.f;     // hoisted scalar loads
    float scale = sc2[k], shift = sc2[C + k];
    fill_D(sm, II, qlast, tile, k, b, xmin, xmax);

    int tid = threadIdx.x;
    size_t base = ((size_t)(b * C + k)) * HW + (size_t)tile * TY * W;
    if (tid < W) {
        float xreg[10];
        #pragma unroll
        for (int j = 0; j < 10; ++j)               // batch-issue x loads
            xreg[j] = x[base + (size_t)j * W + tid];
        ColW c = mk_colw(tid, ylo, yhi);
        #pragma unroll
        for (int j = 0; j < 10; ++j) {
            float v = eval_col(sm, j, c);
            out[base + (size_t)j * W + tid] = fmaxf(xreg[j] + fmaf(scale, v, shift), 0.f);
        }
    } else {
        int t0 = tid - W;                          // 0..95
        float xreg[10];
        int rows[10], cols[10];
        #pragma unroll
        for (int j = 0; j < 10; ++j) {
            int e = t0 + 96 * j;
            rows[j] = 10 + e / 160;
            cols[j] = e - (e / 160) * 160;
            xreg[j] = x[base + (size_t)rows[j] * W + cols[j]];
        }
        #pragma unroll
        for (int j = 0; j < 10; ++j) {
            ColW c = mk_colw(cols[j], ylo, yhi);
            float v = eval_col(sm, rows[j], c);
            out[base + (size_t)rows[j] * W + cols[j]] = fmaxf(xreg[j] + fmaf(scale, v, shift), 0.f);
        }
    }
}

// ---------------- launch ----------------
extern "C" void kernel_launch(void* const* d_in, const int* in_sizes, int n_in,
                              void* d_out, int out_size, void* d_ws, size_t ws_size,
                              hipStream_t stream)
{
    const float* x    = (const float*)d_in[0];
    const float* w1   = (const float*)d_in[1];
    const float* g1   = (const float*)d_in[2];
    const float* b1   = (const float*)d_in[3];
    const float* xmin = (const float*)d_in[4];
    const float* xmax = (const float*)d_in[5];
    const float* ymin = (const float*)d_in[6];
    const float* ymax = (const float*)d_in[7];
    const float* g2   = (const float*)d_in[8];
    const float* b2   = (const float*)d_in[9];
    float* out = (float*)d_out;

    char* ws = (char*)d_ws;
    float* sc2 = (float*)ws;
    float* wTg = (float*)(ws + 1280);
    double* rowsum1 = (double*)(ws + 17664);
    float* h   = (float*)(ws + 20480);
    float* II  = (float*)(ws + 20480 + (size_t)B * CM * HW * sizeof(float));
    float* qlast = (float*)(ws + 20480 + (size_t)B * CM * HW * sizeof(float)
                               + (size_t)B * CM * PLANE * sizeof(float));
    float* part1 = II;   // dead before k_scan_part writes II
    float* part2 = h;    // h dead after k_scan_part

    k_transpose_w<<<dim3((C * CM + 255) / 256), 256, 0, stream>>>(w1, wTg);
    k_conv     <<<dim3(K1B), 256, 0, stream>>>(x, wTg, h, part1);
    k_rowsum1  <<<dim3(2 * CM), 256, 0, stream>>>(part1, rowsum1);
    k_scan_part<<<dim3(B * CM * 4), 256, 0, stream>>>(h, rowsum1, g1, b1, II, qlast);
    k_box_part <<<dim3(NTILE, C, B), 256, 0, stream>>>(II, qlast, xmin, xmax, ymin, ymax, part2);
    k_reduce2  <<<dim3(1), 256, 0, stream>>>(part2, g2, b2, sc2);
    k_box_final<<<dim3(NTILE, C, B), 256, 0, stream>>>(II, qlast, x, xmin, xmax, ymin, ymax,
                                                       sc2, out);
}

// Round 13
// 99.896 us; speedup vs baseline: 1.0716x; 1.0716x over previous
//
#include <hip/hip_runtime.h>
#include <cstdint>

constexpr int B  = 4;
constexpr int C  = 128;
constexpr int CM = 32;        // mid channels
constexpr int H  = 160;
constexpr int W  = 160;
constexpr int HW = H * W;     // 25600
constexpr int HP = H + 1;     // 161
constexpr int WP = W + 1;     // 161
constexpr int PLANE = HP * WP; // 25921
constexpr int TY = 16;         // rows per box tile
constexpr int NTILE = H / TY;  // 10
constexpr int PB  = 64;        // positions per conv block
constexpr int K1B = B * HW / PB; // 1600 conv blocks
constexpr int NB2 = B * NTILE; // 40 partials per out-channel
constexpr int QR = 40;         // rows per scan quarter

// ---------------- K0: transpose w1 [CM][C] -> wTg [C][CM] (16 KB, once) ----------------
__global__ __launch_bounds__(256) void k_transpose_w(
    const float* __restrict__ w1, float* __restrict__ wTg)
{
    int t = blockIdx.x * 256 + threadIdx.x;    // 4096 elements
    if (t < C * CM) {
        int o = t / C, c = t % C;
        wTg[c * CM + o] = w1[t];
    }
}

// ------- K1: 1x1 conv, split-C: wave q owns c in [32q,32q+32), 64 pos/block -------
__global__ __launch_bounds__(256) void k_conv(
    const float* __restrict__ x, const float* __restrict__ wTg,
    float* __restrict__ h, float* __restrict__ part1)
{
    __shared__ float part[4 * CM * PB];   // 32 KB: [q][o][lane]
    int tid = threadIdx.x;
    int wave = tid >> 6, lane = tid & 63;
    int bid = blockIdx.x;                 // 1600 blocks; 400 per batch image
    int b = bid / 400;
    int p0 = (bid % 400) * PB;

    int wq = __builtin_amdgcn_readfirstlane(wave);   // uniform wave id -> SGPR
    const float* xb = x + (size_t)b * C * HW + (size_t)(wq * 32) * HW + p0 + lane;
    const float* wrow = wTg + (size_t)(wq * 32) * CM;  // uniform base -> s_loads

    float acc[CM];
    #pragma unroll
    for (int o = 0; o < CM; ++o) acc[o] = 0.f;

    #pragma unroll 4
    for (int i = 0; i < 32; ++i) {
        float xv = xb[(size_t)i * HW];               // coalesced 256B vector load
        const float* wr = wrow + i * CM;             // uniform -> scalar loads
        #pragma unroll
        for (int o = 0; o < CM; ++o)
            acc[o] = fmaf(wr[o], xv, acc[o]);        // SGPR-operand FMA
    }

    float* pq = &part[wave * CM * PB];
    #pragma unroll
    for (int o = 0; o < CM; ++o) pq[o * PB + lane] = acc[o];
    __syncthreads();

    // final: thread t owns 8 consecutive finals (one o, lanes l0..l0+7)
    int o  = tid >> 3;                 // 0..31
    int l0 = (tid & 7) * 8;
    const float* pp = &part[o * PB + l0];
    float4 f0 = *reinterpret_cast<const float4*>(pp);
    float4 f1 = *reinterpret_cast<const float4*>(pp + 4);
    #pragma unroll
    for (int q = 1; q < 4; ++q) {
        const float4 a0 = *reinterpret_cast<const float4*>(pp + q * CM * PB);
        const float4 a1 = *reinterpret_cast<const float4*>(pp + q * CM * PB + 4);
        f0.x += a0.x; f0.y += a0.y; f0.z += a0.z; f0.w += a0.w;
        f1.x += a1.x; f1.y += a1.y; f1.z += a1.z; f1.w += a1.w;
    }

    float* hb = h + ((size_t)(b * CM + o)) * HW + p0 + l0;
    *reinterpret_cast<float4*>(hb)     = f0;
    *reinterpret_cast<float4*>(hb + 4) = f1;

    float s  = f0.x + f0.y + f0.z + f0.w + f1.x + f1.y + f1.z + f1.w;
    float s2 = f0.x * f0.x + f0.y * f0.y + f0.z * f0.z + f0.w * f0.w
             + f1.x * f1.x + f1.y * f1.y + f1.z * f1.z + f1.w * f1.w;
    #pragma unroll
    for (int off = 4; off > 0; off >>= 1) {
        s  += __shfl_down(s,  off, 8);
        s2 += __shfl_down(s2, off, 8);
    }
    if ((tid & 7) == 0) {
        part1[(size_t)o * K1B + bid]        = s;   // row o      : sums
        part1[(size_t)(o + CM) * K1B + bid] = s2;  // row CM + o : sumsq
    }
}

// ---------------- R1: parallel row-sums (64 blocks, coalesced) ----------------
__global__ __launch_bounds__(256) void k_rowsum1(
    const float* __restrict__ part1, double* __restrict__ rowsum1)
{
    __shared__ double red[256];
    int tid = threadIdx.x;
    int r = blockIdx.x;                      // 0..63
    const float* row = part1 + (size_t)r * K1B;
    double a = 0.0;
    for (int i = tid; i < K1B; i += 256) a += (double)row[i];
    red[tid] = a;
    __syncthreads();
    #pragma unroll
    for (int s = 128; s > 0; s >>= 1) {
        if (tid < s) red[tid] += red[tid + s];
        __syncthreads();
    }
    if (tid == 0) rowsum1[r] = red[0];
}

// ------- K2: BN1 (from rowsum1) + ReLU + row scan + LOCAL col scan per (plane, quarter) -------
__global__ __launch_bounds__(256) void k_scan_part(
    const float* __restrict__ h, const double* __restrict__ rowsum1,
    const float* __restrict__ g1, const float* __restrict__ b1,
    float* __restrict__ II, float* __restrict__ qlast)
{
    __shared__ float buf[QR * W];   // 40 row-scanned rows, 25600 B
    int tid = threadIdx.x;
    int wave = tid >> 6, lane = tid & 63;
    int blk = blockIdx.x;           // plane*4 + q
    int plane = blk >> 2, q = blk & 3;
    int cm = plane & (CM - 1);

    double n = (double)(B * HW);
    double mean = rowsum1[cm] / n;
    double var  = rowsum1[CM + cm] / n - mean * mean;
    float inv   = (float)(1.0 / sqrt(var + 1e-5));
    float scale = g1[cm] * inv;
    float shift = b1[cm] - (float)mean * scale;

    const float* hp = h + (size_t)plane * HW + (size_t)q * QR * W;
    float* IIp = II + (size_t)plane * PLANE;

    if (q == 0) {
        for (int e = tid; e < WP; e += 256) IIp[e] = 0.f;
    }

    for (int y = wave; y < QR; y += 4) {
        const float* hr = hp + (size_t)y * W;
        float carry = 0.f;
        #pragma unroll
        for (int x0 = 0; x0 < W; x0 += 64) {
            int xx = x0 + lane;
            float v = (xx < W) ? fmaxf(fmaf(scale, hr[xx], shift), 0.f) : 0.f;
            #pragma unroll
            for (int off = 1; off < 64; off <<= 1) {
                float t = __shfl_up(v, off);
                if (lane >= off) v += t;
            }
            v += carry;
            if (xx < W) buf[y * W + xx] = v;
            carry = __shfl(v, 63);
        }
    }
    __syncthreads();

    float* op = IIp + (size_t)(q * QR + 1) * WP;
    float* ql = qlast + ((size_t)plane * 3 + q) * WP;
    if (tid <= W) {
        float run = 0.f;
        #pragma unroll 4
        for (int r = 0; r < QR; ++r) {
            float v = 0.f;
            if (tid > 0) { run += buf[r * W + (tid - 1)]; v = run; }
            op[(size_t)r * WP + tid] = v;
            if (r == QR - 1 && q < 3) ql[tid] = v;
        }
    }
}

// ---------------- box tile machinery ----------------
struct BoxSmem {
    float D[TY][WP];      // row-interp difference rows (true II values)
    float coff[4][WP];    // cumulative cross-quarter offsets per column
    int   ru0[2][TY];     // [0]=lo, [1]=hi row coords
    int   ru1[2][TY];
    float rua[2][TY];
    int   rq0[2][TY];     // quarter index of ru0 / ru1
    int   rq1[2][TY];
};

__device__ inline int qidx(int row) { return row == 0 ? 0 : (row - 1) / QR; }

__device__ inline void fill_D(BoxSmem& sm, const float* __restrict__ II,
    const float* __restrict__ qlast,
    int tile, int k, int b,
    const float* __restrict__ xmin, const float* __restrict__ xmax)
{
    int tid = threadIdx.x;
    int plane = b * CM + (k >> 2);
    if (tid < 2 * TY) {
        int side = tid / TY, ty = tid % TY;
        float off = side ? (xmax[k] + 1.f) : xmin[k];
        float u = fminf(fmaxf((float)(tile * TY + ty) + off, 0.f), 160.f);
        float uf = floorf(u);
        int i0 = (int)uf;
        int i1 = min(i0 + 1, 160);
        sm.ru0[side][ty] = i0;
        sm.ru1[side][ty] = i1;
        sm.rua[side][ty] = u - uf;
        sm.rq0[side][ty] = qidx(i0);
        sm.rq1[side][ty] = qidx(i1);
    }
    {
        const float* qb = qlast + (size_t)plane * 3 * WP;
        for (int v = tid; v < WP; v += 256) {
            float l0 = qb[v], l1 = qb[WP + v], l2 = qb[2 * WP + v];
            sm.coff[0][v] = 0.f;
            sm.coff[1][v] = l0;
            sm.coff[2][v] = l0 + l1;
            sm.coff[3][v] = l0 + l1 + l2;
        }
    }
    __syncthreads();

    const float* P = II + (size_t)plane * PLANE;
    int ty = tid / WP, v = tid % WP;
    for (int e = tid; e < TY * WP; e += 256) {
        float al = sm.rua[0][ty], ah = sm.rua[1][ty];
        float lo = (P[(size_t)sm.ru0[0][ty] * WP + v] + sm.coff[sm.rq0[0][ty]][v]) * (1.f - al)
                 + (P[(size_t)sm.ru1[0][ty] * WP + v] + sm.coff[sm.rq1[0][ty]][v]) * al;
        float hi = (P[(size_t)sm.ru0[1][ty] * WP + v] + sm.coff[sm.rq0[1][ty]][v]) * (1.f - ah)
                 + (P[(size_t)sm.ru1[1][ty] * WP + v] + sm.coff[sm.rq1[1][ty]][v]) * ah;
        sm.D[ty][v] = hi - lo;
        ty += 1; v += 95;
        if (v >= WP) { v -= WP; ty += 1; }
    }
    __syncthreads();
}

// per-column hoisted coords
struct ColW { int l0, l1, h0, h1; float la, ha; };

__device__ inline ColW mk_colw(int xx, float ylo, float yhi)
{
    ColW c;
    float v = fminf(fmaxf((float)xx + ylo, 0.f), 160.f);
    float vf = floorf(v);
    c.l0 = (int)vf; c.la = v - vf; c.l1 = min(c.l0 + 1, 160);
    v = fminf(fmaxf((float)xx + yhi, 0.f), 160.f);
    vf = floorf(v);
    c.h0 = (int)vf; c.ha = v - vf; c.h1 = min(c.h0 + 1, 160);
    return c;
}

__device__ inline float eval_col(const BoxSmem& sm, int ty, const ColW& c)
{
    const float* Dr = sm.D[ty];
    return (Dr[c.h0] * (1.f - c.ha) + Dr[c.h1] * c.ha)
         - (Dr[c.l0] * (1.f - c.la) + Dr[c.l1] * c.la);
}

// ---------------- K4: box conv ONCE -> raw values into out + BN2 partial stats ----------------
__global__ __launch_bounds__(256) void k_box_eval(
    const float* __restrict__ II, const float* __restrict__ qlast,
    const float* __restrict__ xmin, const float* __restrict__ xmax,
    const float* __restrict__ ymin, const float* __restrict__ ymax,
    float* __restrict__ part2, float* __restrict__ outraw)
{
    __shared__ BoxSmem sm;
    __shared__ float red[4][2];
    int tile = blockIdx.x, k = blockIdx.y, b = blockIdx.z;
    float ylo = ymin[k], yhi = ymax[k] + 1.f;     // hoisted scalar loads
    fill_D(sm, II, qlast, tile, k, b, xmin, xmax);

    int tid = threadIdx.x;
    float s = 0.f, s2 = 0.f;
    size_t base = ((size_t)(b * C + k)) * HW + (size_t)tile * TY * W;
    if (tid < W) {
        ColW c = mk_colw(tid, ylo, yhi);
        #pragma unroll
        for (int ty = 0; ty < TY; ++ty) {
            float v = eval_col(sm, ty, c);
            outraw[base + (size_t)ty * W + tid] = v;   // row-contiguous store
            s  += v;
            s2 += v * v;
        }
    }
    #pragma unroll
    for (int off = 32; off > 0; off >>= 1) {
        s  += __shfl_down(s,  off);
        s2 += __shfl_down(s2, off);
    }
    int wave = tid >> 6, lane = tid & 63;
    if (lane == 0) { red[wave][0] = s; red[wave][1] = s2; }
    __syncthreads();
    if (tid == 0) {
        int idx = b * NTILE + tile;     // 0..39
        part2[(size_t)k * NB2 + idx]       = red[0][0] + red[1][0] + red[2][0] + red[3][0];
        part2[(size_t)(C + k) * NB2 + idx] = red[0][1] + red[1][1] + red[2][1] + red[3][1];
    }
}

// ---------------- R2: deterministic reduction -> BN2 scale/shift ----------------
__global__ __launch_bounds__(256) void k_reduce2(
    const float* __restrict__ part2, const float* __restrict__ g2,
    const float* __restrict__ b2, float* __restrict__ sc2)
{
    __shared__ double dsum[2 * C];
    int t = threadIdx.x;                 // 256 rows, one per thread
    const float4* rp = reinterpret_cast<const float4*>(part2 + (size_t)t * NB2);
    double acc = 0.0;
    #pragma unroll
    for (int i = 0; i < NB2 / 4; ++i) {
        float4 v = rp[i];
        acc += (double)v.x + (double)v.y + (double)v.z + (double)v.w;
    }
    dsum[t] = acc;
    __syncthreads();
    if (t < C) {
        double n = (double)(B * HW);
        double mean = dsum[t] / n;
        double var  = dsum[C + t] / n - mean * mean;
        float inv   = (float)(1.0 / sqrt(var + 1e-5));
        float scale = g2[t] * inv;
        sc2[t]     = scale;
        sc2[C + t] = b2[t] - (float)mean * scale;
    }
}

// ---------------- K5: pure streaming finalize: out = relu(x + scale*out + shift) ----------------
__global__ __launch_bounds__(256) void k_finalize(
    const float* __restrict__ x, const float* __restrict__ sc2,
    float* __restrict__ out)
{
    int bid = blockIdx.x;                 // B*C*25 = 12800 blocks
    int p = bid / 25;                     // plane b*C+k
    int k = p & (C - 1);
    float scale = sc2[k], shift = sc2[C + k];
    size_t idx4 = (size_t)p * (HW / 4) + (size_t)(bid % 25) * 256 + threadIdx.x;

    float4 o  = reinterpret_cast<const float4*>(out)[idx4];
    float4 xv = reinterpret_cast<const float4*>(x)[idx4];
    float4 r;
    r.x = fmaxf(xv.x + fmaf(scale, o.x, shift), 0.f);
    r.y = fmaxf(xv.y + fmaf(scale, o.y, shift), 0.f);
    r.z = fmaxf(xv.z + fmaf(scale, o.z, shift), 0.f);
    r.w = fmaxf(xv.w + fmaf(scale, o.w, shift), 0.f);
    reinterpret_cast<float4*>(out)[idx4] = r;
}

// ---------------- launch ----------------
extern "C" void kernel_launch(void* const* d_in, const int* in_sizes, int n_in,
                              void* d_out, int out_size, void* d_ws, size_t ws_size,
                              hipStream_t stream)
{
    const float* x    = (const float*)d_in[0];
    const float* w1   = (const float*)d_in[1];
    const float* g1   = (const float*)d_in[2];
    const float* b1   = (const float*)d_in[3];
    const float* xmin = (const float*)d_in[4];
    const float* xmax = (const float*)d_in[5];
    const float* ymin = (const float*)d_in[6];
    const float* ymax = (const float*)d_in[7];
    const float* g2   = (const float*)d_in[8];
    const float* b2   = (const float*)d_in[9];
    float* out = (float*)d_out;

    char* ws = (char*)d_ws;
    float* sc2 = (float*)ws;
    float* wTg = (float*)(ws + 1280);
    double* rowsum1 = (double*)(ws + 17664);
    float* h   = (float*)(ws + 20480);
    float* II  = (float*)(ws + 20480 + (size_t)B * CM * HW * sizeof(float));
    float* qlast = (float*)(ws + 20480 + (size_t)B * CM * HW * sizeof(float)
                               + (size_t)B * CM * PLANE * sizeof(float));
    float* part1 = II;   // dead before k_scan_part writes II
    float* part2 = h;    // h dead after k_scan_part

    k_transpose_w<<<dim3((C * CM + 255) / 256), 256, 0, stream>>>(w1, wTg);
    k_conv     <<<dim3(K1B), 256, 0, stream>>>(x, wTg, h, part1);
    k_rowsum1  <<<dim3(2 * CM), 256, 0, stream>>>(part1, rowsum1);
    k_scan_part<<<dim3(B * CM * 4), 256, 0, stream>>>(h, rowsum1, g1, b1, II, qlast);
    k_box_eval <<<dim3(NTILE, C, B), 256, 0, stream>>>(II, qlast, xmin, xmax, ymin, ymax,
                                                       part2, out);
    k_reduce2  <<<dim3(1), 256, 0, stream>>>(part2, g2, b2, sc2);
    k_finalize <<<dim3(B * C * 25), 256, 0, stream>>>(x, sc2, out);
}

// Round 14
// 97.295 us; speedup vs baseline: 1.1003x; 1.0267x over previous
//
#include <hip/hip_runtime.h>
#include <hip/hip_fp16.h>
#include <cstdint>

constexpr int B  = 4;
constexpr int C  = 128;
constexpr int CM = 32;        // mid channels
constexpr int H  = 160;
constexpr int W  = 160;
constexpr int HW = H * W;     // 25600
constexpr int HP = H + 1;     // 161
constexpr int WP = W + 1;     // 161
constexpr int PLANE = HP * WP; // 25921
constexpr int TY = 16;         // rows per box tile
constexpr int NTILE = H / TY;  // 10
constexpr int PB  = 64;        // positions per conv block
constexpr int K1B = B * HW / PB; // 1600 conv blocks
constexpr int NB2 = B * NTILE; // 40 partials per out-channel
constexpr int QR = 40;         // rows per scan quarter

// ---------------- K0: transpose w1 [CM][C] -> wTg [C][CM] (16 KB, once) ----------------
__global__ __launch_bounds__(256) void k_transpose_w(
    const float* __restrict__ w1, float* __restrict__ wTg)
{
    int t = blockIdx.x * 256 + threadIdx.x;    // 4096 elements
    if (t < C * CM) {
        int o = t / C, c = t % C;
        wTg[c * CM + o] = w1[t];
    }
}

// ------- K1: 1x1 conv, split-C: wave q owns c in [32q,32q+32), 64 pos/block -------
__global__ __launch_bounds__(256) void k_conv(
    const float* __restrict__ x, const float* __restrict__ wTg,
    float* __restrict__ h, float* __restrict__ part1)
{
    __shared__ float part[4 * CM * PB];   // 32 KB: [q][o][lane]
    int tid = threadIdx.x;
    int wave = tid >> 6, lane = tid & 63;
    int bid = blockIdx.x;                 // 1600 blocks; 400 per batch image
    int b = bid / 400;
    int p0 = (bid % 400) * PB;

    int wq = __builtin_amdgcn_readfirstlane(wave);   // uniform wave id -> SGPR
    const float* xb = x + (size_t)b * C * HW + (size_t)(wq * 32) * HW + p0 + lane;
    const float* wrow = wTg + (size_t)(wq * 32) * CM;  // uniform base -> s_loads

    float acc[CM];
    #pragma unroll
    for (int o = 0; o < CM; ++o) acc[o] = 0.f;

    #pragma unroll 8
    for (int i = 0; i < 32; ++i) {
        float xv = xb[(size_t)i * HW];               // coalesced 256B vector load
        const float* wr = wrow + i * CM;             // uniform -> scalar loads
        #pragma unroll
        for (int o = 0; o < CM; ++o)
            acc[o] = fmaf(wr[o], xv, acc[o]);        // SGPR-operand FMA
    }

    float* pq = &part[wave * CM * PB];
    #pragma unroll
    for (int o = 0; o < CM; ++o) pq[o * PB + lane] = acc[o];
    __syncthreads();

    // final: thread t owns 8 consecutive finals (one o, lanes l0..l0+7)
    int o  = tid >> 3;                 // 0..31
    int l0 = (tid & 7) * 8;
    const float* pp = &part[o * PB + l0];
    float4 f0 = *reinterpret_cast<const float4*>(pp);
    float4 f1 = *reinterpret_cast<const float4*>(pp + 4);
    #pragma unroll
    for (int q = 1; q < 4; ++q) {
        const float4 a0 = *reinterpret_cast<const float4*>(pp + q * CM * PB);
        const float4 a1 = *reinterpret_cast<const float4*>(pp + q * CM * PB + 4);
        f0.x += a0.x; f0.y += a0.y; f0.z += a0.z; f0.w += a0.w;
        f1.x += a1.x; f1.y += a1.y; f1.z += a1.z; f1.w += a1.w;
    }

    float* hb = h + ((size_t)(b * CM + o)) * HW + p0 + l0;
    *reinterpret_cast<float4*>(hb)     = f0;
    *reinterpret_cast<float4*>(hb + 4) = f1;

    float s  = f0.x + f0.y + f0.z + f0.w + f1.x + f1.y + f1.z + f1.w;
    float s2 = f0.x * f0.x + f0.y * f0.y + f0.z * f0.z + f0.w * f0.w
             + f1.x * f1.x + f1.y * f1.y + f1.z * f1.z + f1.w * f1.w;
    #pragma unroll
    for (int off = 4; off > 0; off >>= 1) {
        s  += __shfl_down(s,  off, 8);
        s2 += __shfl_down(s2, off, 8);
    }
    if ((tid & 7) == 0) {
        part1[(size_t)o * K1B + bid]        = s;   // row o      : sums
        part1[(size_t)(o + CM) * K1B + bid] = s2;  // row CM + o : sumsq
    }
}

// ---------------- R1: parallel row-sums (64 blocks, coalesced) ----------------
__global__ __launch_bounds__(256) void k_rowsum1(
    const float* __restrict__ part1, double* __restrict__ rowsum1)
{
    __shared__ double red[256];
    int tid = threadIdx.x;
    int r = blockIdx.x;                      // 0..63
    const float* row = part1 + (size_t)r * K1B;
    double a = 0.0;
    for (int i = tid; i < K1B; i += 256) a += (double)row[i];
    red[tid] = a;
    __syncthreads();
    #pragma unroll
    for (int s = 128; s > 0; s >>= 1) {
        if (tid < s) red[tid] += red[tid + s];
        __syncthreads();
    }
    if (tid == 0) rowsum1[r] = red[0];
}

// ------- K2: BN1 (from rowsum1) + ReLU + row scan + LOCAL col scan per (plane, quarter) -------
__global__ __launch_bounds__(256) void k_scan_part(
    const float* __restrict__ h, const double* __restrict__ rowsum1,
    const float* __restrict__ g1, const float* __restrict__ b1,
    float* __restrict__ II, float* __restrict__ qlast)
{
    __shared__ float buf[QR * W];   // 40 row-scanned rows, 25600 B
    int tid = threadIdx.x;
    int wave = tid >> 6, lane = tid & 63;
    int blk = blockIdx.x;           // plane*4 + q
    int plane = blk >> 2, q = blk & 3;
    int cm = plane & (CM - 1);

    double n = (double)(B * HW);
    double mean = rowsum1[cm] / n;
    double var  = rowsum1[CM + cm] / n - mean * mean;
    float inv   = (float)(1.0 / sqrt(var + 1e-5));
    float scale = g1[cm] * inv;
    float shift = b1[cm] - (float)mean * scale;

    const float* hp = h + (size_t)plane * HW + (size_t)q * QR * W;
    float* IIp = II + (size_t)plane * PLANE;

    if (q == 0) {
        for (int e = tid; e < WP; e += 256) IIp[e] = 0.f;
    }

    for (int y = wave; y < QR; y += 4) {
        const float* hr = hp + (size_t)y * W;
        float carry = 0.f;
        #pragma unroll
        for (int x0 = 0; x0 < W; x0 += 64) {
            int xx = x0 + lane;
            float v = (xx < W) ? fmaxf(fmaf(scale, hr[xx], shift), 0.f) : 0.f;
            #pragma unroll
            for (int off = 1; off < 64; off <<= 1) {
                float t = __shfl_up(v, off);
                if (lane >= off) v += t;
            }
            v += carry;
            if (xx < W) buf[y * W + xx] = v;
            carry = __shfl(v, 63);
        }
    }
    __syncthreads();

    float* op = IIp + (size_t)(q * QR + 1) * WP;
    float* ql = qlast + ((size_t)plane * 3 + q) * WP;
    if (tid <= W) {
        float run = 0.f;
        #pragma unroll 4
        for (int r = 0; r < QR; ++r) {
            float v = 0.f;
            if (tid > 0) { run += buf[r * W + (tid - 1)]; v = run; }
            op[(size_t)r * WP + tid] = v;
            if (r == QR - 1 && q < 3) ql[tid] = v;
        }
    }
}

// ---------------- box tile machinery ----------------
struct BoxSmem {
    float D[TY][WP];      // row-interp difference rows (true II values)
    float coff[4][WP];    // cumulative cross-quarter offsets per column
    int   ru0[2][TY];     // [0]=lo, [1]=hi row coords
    int   ru1[2][TY];
    float rua[2][TY];
    int   rq0[2][TY];     // quarter index of ru0 / ru1
    int   rq1[2][TY];
};

__device__ inline int qidx(int row) { return row == 0 ? 0 : (row - 1) / QR; }

__device__ inline void fill_D(BoxSmem& sm, const float* __restrict__ II,
    const float* __restrict__ qlast,
    int tile, int k, int b,
    const float* __restrict__ xmin, const float* __restrict__ xmax)
{
    int tid = threadIdx.x;
    int plane = b * CM + (k >> 2);
    if (tid < 2 * TY) {
        int side = tid / TY, ty = tid % TY;
        float off = side ? (xmax[k] + 1.f) : xmin[k];
        float u = fminf(fmaxf((float)(tile * TY + ty) + off, 0.f), 160.f);
        float uf = floorf(u);
        int i0 = (int)uf;
        int i1 = min(i0 + 1, 160);
        sm.ru0[side][ty] = i0;
        sm.ru1[side][ty] = i1;
        sm.rua[side][ty] = u - uf;
        sm.rq0[side][ty] = qidx(i0);
        sm.rq1[side][ty] = qidx(i1);
    }
    {
        const float* qb = qlast + (size_t)plane * 3 * WP;
        for (int v = tid; v < WP; v += 256) {
            float l0 = qb[v], l1 = qb[WP + v], l2 = qb[2 * WP + v];
            sm.coff[0][v] = 0.f;
            sm.coff[1][v] = l0;
            sm.coff[2][v] = l0 + l1;
            sm.coff[3][v] = l0 + l1 + l2;
        }
    }
    __syncthreads();

    const float* P = II + (size_t)plane * PLANE;
    int ty = tid / WP, v = tid % WP;
    for (int e = tid; e < TY * WP; e += 256) {
        float al = sm.rua[0][ty], ah = sm.rua[1][ty];
        float lo = (P[(size_t)sm.ru0[0][ty] * WP + v] + sm.coff[sm.rq0[0][ty]][v]) * (1.f - al)
                 + (P[(size_t)sm.ru1[0][ty] * WP + v] + sm.coff[sm.rq1[0][ty]][v]) * al;
        float hi = (P[(size_t)sm.ru0[1][ty] * WP + v] + sm.coff[sm.rq0[1][ty]][v]) * (1.f - ah)
                 + (P[(size_t)sm.ru1[1][ty] * WP + v] + sm.coff[sm.rq1[1][ty]][v]) * ah;
        sm.D[ty][v] = hi - lo;
        ty += 1; v += 95;
        if (v >= WP) { v -= WP; ty += 1; }
    }
    __syncthreads();
}

// per-column hoisted coords
struct ColW { int l0, l1, h0, h1; float la, ha; };

__device__ inline ColW mk_colw(int xx, float ylo, float yhi)
{
    ColW c;
    float v = fminf(fmaxf((float)xx + ylo, 0.f), 160.f);
    float vf = floorf(v);
    c.l0 = (int)vf; c.la = v - vf; c.l1 = min(c.l0 + 1, 160);
    v = fminf(fmaxf((float)xx + yhi, 0.f), 160.f);
    vf = floorf(v);
    c.h0 = (int)vf; c.ha = v - vf; c.h1 = min(c.h0 + 1, 160);
    return c;
}

__device__ inline float eval_col(const BoxSmem& sm, int ty, const ColW& c)
{
    const float* Dr = sm.D[ty];
    return (Dr[c.h0] * (1.f - c.ha) + Dr[c.h1] * c.ha)
         - (Dr[c.l0] * (1.f - c.la) + Dr[c.l1] * c.la);
}

// ---------------- K4: box conv ONCE -> fp16 raw into ws + BN2 partial stats ----------------
__global__ __launch_bounds__(256) void k_box_eval(
    const float* __restrict__ II, const float* __restrict__ qlast,
    const float* __restrict__ xmin, const float* __restrict__ xmax,
    const float* __restrict__ ymin, const float* __restrict__ ymax,
    float* __restrict__ part2, __half* __restrict__ raw)
{
    __shared__ BoxSmem sm;
    __shared__ float red[4][2];
    int tile = blockIdx.x, k = blockIdx.y, b = blockIdx.z;
    float ylo = ymin[k], yhi = ymax[k] + 1.f;     // hoisted scalar loads
    fill_D(sm, II, qlast, tile, k, b, xmin, xmax);

    int tid = threadIdx.x;
    float s = 0.f, s2 = 0.f;
    size_t base = ((size_t)(b * C + k)) * HW + (size_t)tile * TY * W;
    if (tid < W) {
        ColW c = mk_colw(tid, ylo, yhi);
        #pragma unroll
        for (int ty = 0; ty < TY; ++ty) {
            float v = eval_col(sm, ty, c);
            raw[base + (size_t)ty * W + tid] = __float2half(v);   // row-contiguous
            s  += v;
            s2 += v * v;
        }
    }
    #pragma unroll
    for (int off = 32; off > 0; off >>= 1) {
        s  += __shfl_down(s,  off);
        s2 += __shfl_down(s2, off);
    }
    int wave = tid >> 6, lane = tid & 63;
    if (lane == 0) { red[wave][0] = s; red[wave][1] = s2; }
    __syncthreads();
    if (tid == 0) {
        int idx = b * NTILE + tile;     // 0..39
        part2[(size_t)k * NB2 + idx]       = red[0][0] + red[1][0] + red[2][0] + red[3][0];
        part2[(size_t)(C + k) * NB2 + idx] = red[0][1] + red[1][1] + red[2][1] + red[3][1];
    }
}

// ---------------- R2: deterministic reduction -> BN2 scale/shift ----------------
__global__ __launch_bounds__(256) void k_reduce2(
    const float* __restrict__ part2, const float* __restrict__ g2,
    const float* __restrict__ b2, float* __restrict__ sc2)
{
    __shared__ double dsum[2 * C];
    int t = threadIdx.x;                 // 256 rows, one per thread
    const float4* rp = reinterpret_cast<const float4*>(part2 + (size_t)t * NB2);
    double acc = 0.0;
    #pragma unroll
    for (int i = 0; i < NB2 / 4; ++i) {
        float4 v = rp[i];
        acc += (double)v.x + (double)v.y + (double)v.z + (double)v.w;
    }
    dsum[t] = acc;
    __syncthreads();
    if (t < C) {
        double n = (double)(B * HW);
        double mean = dsum[t] / n;
        double var  = dsum[C + t] / n - mean * mean;
        float inv   = (float)(1.0 / sqrt(var + 1e-5));
        float scale = g2[t] * inv;
        sc2[t]     = scale;
        sc2[C + t] = b2[t] - (float)mean * scale;
    }
}

// ---------------- K5: streaming finalize: out = relu(x + scale*raw + shift) ----------------
__global__ __launch_bounds__(256) void k_finalize(
    const float* __restrict__ x, const float* __restrict__ sc2,
    const __half* __restrict__ raw, float* __restrict__ out)
{
    int bid = blockIdx.x;                 // B*C*25 = 12800 blocks
    int p = bid / 25;                     // plane b*C+k
    int k = p & (C - 1);
    float scale = sc2[k], shift = sc2[C + k];
    size_t idx4 = (size_t)p * (HW / 4) + (size_t)(bid % 25) * 256 + threadIdx.x;

    const __half2* r2 = reinterpret_cast<const __half2*>(raw);
    __half2 ha = r2[idx4 * 2];
    __half2 hb = r2[idx4 * 2 + 1];
    float2 a2 = __half22float2(ha);
    float2 b2 = __half22float2(hb);
    float4 xv = reinterpret_cast<const float4*>(x)[idx4];
    float4 r;
    r.x = fmaxf(xv.x + fmaf(scale, a2.x, shift), 0.f);
    r.y = fmaxf(xv.y + fmaf(scale, a2.y, shift), 0.f);
    r.z = fmaxf(xv.z + fmaf(scale, b2.x, shift), 0.f);
    r.w = fmaxf(xv.w + fmaf(scale, b2.y, shift), 0.f);
    reinterpret_cast<float4*>(out)[idx4] = r;
}

// ---------------- launch ----------------
extern "C" void kernel_launch(void* const* d_in, const int* in_sizes, int n_in,
                              void* d_out, int out_size, void* d_ws, size_t ws_size,
                              hipStream_t stream)
{
    const float* x    = (const float*)d_in[0];
    const float* w1   = (const float*)d_in[1];
    const float* g1   = (const float*)d_in[2];
    const float* b1   = (const float*)d_in[3];
    const float* xmin = (const float*)d_in[4];
    const float* xmax = (const float*)d_in[5];
    const float* ymin = (const float*)d_in[6];
    const float* ymax = (const float*)d_in[7];
    const float* g2   = (const float*)d_in[8];
    const float* b2   = (const float*)d_in[9];
    float* out = (float*)d_out;

    // ws layout:
    //   [0,1024)      sc2
    //   [1280,+16K)   wTg
    //   [17664,+512)  rowsum1
    //   [20480,+13107200)       h (fp32)  | first 41 KB reused as part2
    //   [+13107200,+13276672)   II        | first 410 KB reused as part1
    //   then qlast (B*CM*3*WP floats ≈ 247 KB)
    //   then raw (B*C*HW halfs = 26.2 MB)
    char* ws = (char*)d_ws;
    float* sc2 = (float*)ws;
    float* wTg = (float*)(ws + 1280);
    double* rowsum1 = (double*)(ws + 17664);
    float* h   = (float*)(ws + 20480);
    float* II  = (float*)(ws + 20480 + (size_t)B * CM * HW * sizeof(float));
    float* qlast = (float*)(ws + 20480 + (size_t)B * CM * HW * sizeof(float)
                               + (size_t)B * CM * PLANE * sizeof(float));
    __half* raw = (__half*)((char*)qlast + (size_t)B * CM * 3 * WP * sizeof(float) + 256);
    float* part1 = II;   // dead before k_scan_part writes II
    float* part2 = h;    // h dead after k_scan_part

    k_transpose_w<<<dim3((C * CM + 255) / 256), 256, 0, stream>>>(w1, wTg);
    k_conv     <<<dim3(K1B), 256, 0, stream>>>(x, wTg, h, part1);
    k_rowsum1  <<<dim3(2 * CM), 256, 0, stream>>>(part1, rowsum1);
    k_scan_part<<<dim3(B * CM * 4), 256, 0, stream>>>(h, rowsum1, g1, b1, II, qlast);
    k_box_eval <<<dim3(NTILE, C, B), 256, 0, stream>>>(II, qlast, xmin, xmax, ymin, ymax,
                                                       part2, raw);
    k_reduce2  <<<dim3(1), 256, 0, stream>>>(part2, g2, b2, sc2);
    k_finalize <<<dim3(B * C * 25), 256, 0, stream>>>(x, sc2, raw, out);
}